// Round 6
// baseline (173.031 us; speedup 1.0000x reference)
//
#include <hip/hip_runtime.h>
#include <math.h>

#define HDIM 512
#define WAVES_PER_BLOCK 4
#define HCHUNK (HDIM / WAVES_PER_BLOCK)   // 128 hidden units per wave
#define SPL 4                             // samples per lane
#define SPB (64 * SPL)                    // 256 samples per block
#define EPS_DIAG 0.1f
#define NPART 15
#define PSTRIDE 17                        // odd stride -> <=2-way LDS bank aliasing (free)
#define REC 36                            // packed weight record: 33 used + 3 pad

// Odd degree-7 polynomial tanh on clamp(x, -2, 2).
// Pre-activation sigma <= ~0.3 => |x| rarely exceeds ~1.8 (max |w_row| ~0.55
// x 5.3-sigma ~ 2.9 worst case, clamp handles it). Interior max error ~0.01.
__device__ __forceinline__ float poly_tanh(float x) {
    const float C0 = 0.993654f;
    const float C1 = -0.29463f;
    const float C2 = 0.0695331f;
    const float C3 = -0.00696328f;
    float t = fminf(fmaxf(x, -2.0f), 2.0f);
    float u = t * t;
    float p = fmaf(C3, u, C2);
    p = fmaf(p, u, C1);
    p = fmaf(p, u, C0);
    return t * p;
}

// Pack all per-h weights/biases into one contiguous 36-dword record:
// [0..2] W1m col h, [3] b1m, [4..6] W1g col h, [7] b1g,
// [8..16] W1k col h, [17] b1k, [18..26] W2m row h, [27..29] W2g row h,
// [30..32] W2k row h. One linear uniform stream -> batched s_load_dwordx16.
__global__ void pack_weights(const float* __restrict__ W1m, const float* __restrict__ b1m,
                             const float* __restrict__ W2m,
                             const float* __restrict__ W1g, const float* __restrict__ b1g,
                             const float* __restrict__ W2g,
                             const float* __restrict__ W1k, const float* __restrict__ b1k,
                             const float* __restrict__ W2k,
                             float* __restrict__ rec)
{
    const int h = blockIdx.x * blockDim.x + threadIdx.x;
    if (h >= HDIM) return;
    float* r = rec + h * REC;
    r[0] = W1m[0*HDIM+h]; r[1] = W1m[1*HDIM+h]; r[2] = W1m[2*HDIM+h]; r[3] = b1m[h];
    r[4] = W1g[0*HDIM+h]; r[5] = W1g[1*HDIM+h]; r[6] = W1g[2*HDIM+h]; r[7] = b1g[h];
    #pragma unroll
    for (int j = 0; j < 9; ++j) r[8+j] = W1k[j*HDIM+h];
    r[17] = b1k[h];
    #pragma unroll
    for (int j = 0; j < 9; ++j) r[18+j] = W2m[h*9+j];
    r[27] = W2g[h*3+0]; r[28] = W2g[h*3+1]; r[29] = W2g[h*3+2];
    r[30] = W2k[h*3+0]; r[31] = W2k[h*3+1]; r[32] = W2k[h*3+2];
    r[33] = 0.f; r[34] = 0.f; r[35] = 0.f;
}

__global__ __launch_bounds__(256, 3) void dyn_kernel(
    const float* __restrict__ rec,
    const float* __restrict__ q, const float* __restrict__ q_dot,
    const float* __restrict__ s, const float* __restrict__ s_Ddot,
    const float* __restrict__ tau,
    const float* __restrict__ fv, const float* __restrict__ fc,
    const float* __restrict__ b2m, const float* __restrict__ b2g,
    const float* __restrict__ b2k,
    float* __restrict__ out, int n)
{
    // Waves 1..3 deposit partials; wave 0 keeps its own in registers.
    __shared__ float part[WAVES_PER_BLOCK - 1][SPB][PSTRIDE];

    const int lane = threadIdx.x & 63;
    // Wave id in SGPR so the packed-record address stream is provably
    // wave-uniform -> s_load (SMEM broadcast), not per-lane VMEM.
    const int w = __builtin_amdgcn_readfirstlane((int)(threadIdx.x >> 6));
    const int base = blockIdx.x * SPB;

    float in[SPL][9];
    float acc[SPL][NPART];
    #pragma unroll
    for (int ss = 0; ss < SPL; ++ss) {
        const int i = base + ss*64 + lane;
        const int ic = (i < n) ? i : 0;
        in[ss][0] = q[3*ic+0];      in[ss][1] = q[3*ic+1];      in[ss][2] = q[3*ic+2];
        in[ss][3] = s[3*ic+0];      in[ss][4] = s[3*ic+1];      in[ss][5] = s[3*ic+2];
        in[ss][6] = s_Ddot[3*ic+0]; in[ss][7] = s_Ddot[3*ic+1]; in[ss][8] = s_Ddot[3*ic+2];
        #pragma unroll
        for (int c = 0; c < NPART; ++c) acc[ss][c] = 0.f;
    }

    const float* rp = rec + (size_t)(w * HCHUNK) * REC;

    #pragma unroll 2
    for (int hh = 0; hh < HCHUNK; ++hh) {
        // One linear 33-dword uniform load (wv[] lives in SGPRs).
        float wv[33];
        #pragma unroll
        for (int j = 0; j < 33; ++j) wv[j] = rp[j];
        rp += REC;

        #pragma unroll
        for (int ss = 0; ss < SPL; ++ss) {
            float pm = fmaf(in[ss][2], wv[2], fmaf(in[ss][1], wv[1], fmaf(in[ss][0], wv[0], wv[3])));
            float pg = fmaf(in[ss][2], wv[6], fmaf(in[ss][1], wv[5], fmaf(in[ss][0], wv[4], wv[7])));
            float pk = wv[17];
            #pragma unroll
            for (int j = 0; j < 9; ++j) pk = fmaf(in[ss][j], wv[8+j], pk);

            const float hm = poly_tanh(pm);
            const float hg = poly_tanh(pg);
            const float hk = poly_tanh(pk);

            #pragma unroll
            for (int j = 0; j < 9; ++j) acc[ss][j]    = fmaf(hm, wv[18+j], acc[ss][j]);
            #pragma unroll
            for (int j = 0; j < 3; ++j) acc[ss][9+j]  = fmaf(hg, wv[27+j], acc[ss][9+j]);
            #pragma unroll
            for (int j = 0; j < 3; ++j) acc[ss][12+j] = fmaf(hk, wv[30+j], acc[ss][12+j]);
        }
    }

    if (w != 0) {
        #pragma unroll
        for (int ss = 0; ss < SPL; ++ss) {
            float* dst = &part[w-1][ss*64 + lane][0];
            #pragma unroll
            for (int c = 0; c < NPART; ++c) dst[c] = acc[ss][c];
        }
    }
    __syncthreads();
    if (w != 0) return;

    // Wave 0: fold in the three deposited partial sets.
    #pragma unroll
    for (int ss = 0; ss < SPL; ++ss) {
        const int slot = ss*64 + lane;
        #pragma unroll
        for (int c = 0; c < NPART; ++c)
            acc[ss][c] += part[0][slot][c] + part[1][slot][c] + part[2][slot][c];
    }

    // Epilogue scalars (wave-uniform).
    const float fv0 = fv[0], fv1 = fv[1], fv2 = fv[2];
    const float fc0 = fc[0], fc1 = fc[1], fc2 = fc[2];
    const float e2m0 = b2m[0], e2m1 = b2m[1], e2m2 = b2m[2],
                e2m3 = b2m[3], e2m4 = b2m[4], e2m5 = b2m[5],
                e2m6 = b2m[6], e2m7 = b2m[7], e2m8 = b2m[8];
    const float e2g0 = b2g[0], e2g1 = b2g[1], e2g2 = b2g[2];
    const float e2k0 = b2k[0], e2k1 = b2k[1], e2k2 = b2k[2];

    #pragma unroll
    for (int ss = 0; ss < SPL; ++ss) {
        const int i = base + ss*64 + lane;
        if (i >= n) continue;

        const float bM0 = acc[ss][0] + e2m0, bM1 = acc[ss][1] + e2m1, bM2 = acc[ss][2] + e2m2;
        const float bM3 = acc[ss][3] + e2m3, bM4 = acc[ss][4] + e2m4, bM5 = acc[ss][5] + e2m5;
        const float bM6 = acc[ss][6] + e2m6, bM7 = acc[ss][7] + e2m7, bM8 = acc[ss][8] + e2m8;
        const float bG0 = acc[ss][9]  + e2g0, bG1 = acc[ss][10] + e2g1, bG2 = acc[ss][11] + e2g2;
        const float bK0 = acc[ss][12] + e2k0, bK1 = acc[ss][13] + e2k1, bK2 = acc[ss][14] + e2k2;

        // M = Mraw @ Mraw^T + eps*I
        const float m00 = bM0*bM0 + bM1*bM1 + bM2*bM2 + EPS_DIAG;
        const float m01 = bM0*bM3 + bM1*bM4 + bM2*bM5;
        const float m02 = bM0*bM6 + bM1*bM7 + bM2*bM8;
        const float m11 = bM3*bM3 + bM4*bM4 + bM5*bM5 + EPS_DIAG;
        const float m12 = bM3*bM6 + bM4*bM7 + bM5*bM8;
        const float m22 = bM6*bM6 + bM7*bM7 + bM8*bM8 + EPS_DIAG;

        // rhs = -G + KAB - fv*q_dot - fc*sign(q_dot) + tau
        const float qd0 = q_dot[3*i+0], qd1 = q_dot[3*i+1], qd2 = q_dot[3*i+2];
        const float t0 = tau[3*i+0], t1 = tau[3*i+1], t2 = tau[3*i+2];
        const float sg0 = (qd0 > 0.f) ? 1.f : ((qd0 < 0.f) ? -1.f : 0.f);
        const float sg1 = (qd1 > 0.f) ? 1.f : ((qd1 < 0.f) ? -1.f : 0.f);
        const float sg2 = (qd2 > 0.f) ? 1.f : ((qd2 < 0.f) ? -1.f : 0.f);
        const float r0 = -bG0 + bK0 - fv0*qd0 - fc0*sg0 + t0;
        const float r1 = -bG1 + bK1 - fv1*qd1 - fc1*sg1 + t1;
        const float r2 = -bG2 + bK2 - fv2*qd2 - fc2*sg2 + t2;

        // Symmetric 3x3 inverse via adjugate (M SPD, det >= ~1e-3).
        const float c00 = m11*m22 - m12*m12;
        const float c01 = m02*m12 - m01*m22;
        const float c02 = m01*m12 - m02*m11;
        const float det = m00*c00 + m01*c01 + m02*c02;
        const float idet = 1.0f / det;
        const float i11 = m00*m22 - m02*m02;
        const float i12 = m01*m02 - m00*m12;
        const float i22 = m00*m11 - m01*m01;

        out[3*i+0] = (c00*r0 + c01*r1 + c02*r2) * idet;
        out[3*i+1] = (c01*r0 + i11*r1 + i12*r2) * idet;
        out[3*i+2] = (c02*r0 + i12*r1 + i22*r2) * idet;
    }
}

extern "C" void kernel_launch(void* const* d_in, const int* in_sizes, int n_in,
                              void* d_out, int out_size, void* d_ws, size_t ws_size,
                              hipStream_t stream) {
    const float* q      = (const float*)d_in[0];
    const float* q_dot  = (const float*)d_in[1];
    const float* s      = (const float*)d_in[2];
    const float* s_Ddot = (const float*)d_in[3];
    const float* tau    = (const float*)d_in[4];
    const float* fv     = (const float*)d_in[5];
    const float* fc     = (const float*)d_in[6];
    const float* W1m    = (const float*)d_in[7];
    const float* b1m    = (const float*)d_in[8];
    const float* W2m    = (const float*)d_in[9];
    const float* b2m    = (const float*)d_in[10];
    const float* W1g    = (const float*)d_in[11];
    const float* b1g    = (const float*)d_in[12];
    const float* W2g    = (const float*)d_in[13];
    const float* b2g    = (const float*)d_in[14];
    const float* W1k    = (const float*)d_in[15];
    const float* b1k    = (const float*)d_in[16];
    const float* W2k    = (const float*)d_in[17];
    const float* b2k    = (const float*)d_in[18];
    float* out = (float*)d_out;
    float* rec = (float*)d_ws;               // needs HDIM*REC*4 = 73728 B

    const int n = in_sizes[0] / 3;           // B = 131072

    pack_weights<<<(HDIM + 255) / 256, 256, 0, stream>>>(
        W1m, b1m, W2m, W1g, b1g, W2g, W1k, b1k, W2k, rec);

    const int blocks = (n + SPB - 1) / SPB;  // 512 blocks x 256 threads
    dyn_kernel<<<blocks, 256, 0, stream>>>(rec, q, q_dot, s, s_Ddot, tau, fv, fc,
                                           b2m, b2g, b2k, out, n);
}

// Round 7
// 162.830 us; speedup vs baseline: 1.0626x; 1.0626x over previous
//
#include <hip/hip_runtime.h>
#include <math.h>

#define HDIM 512
#define WAVES_PER_BLOCK 4
#define HCHUNK (HDIM / WAVES_PER_BLOCK)   // 128 hidden units per wave
#define SPL 2                             // samples per lane (S=4 spilled; S=2 fits)
#define SPB (64 * SPL)                    // 128 samples per block
#define EPS_DIAG 0.1f
#define NPART 15
#define PSTRIDE 17                        // odd stride -> <=2-way LDS bank aliasing (free)
#define REC 36                            // packed weight record: 33 used + 3 pad

// Odd degree-7 polynomial tanh on clamp(x, -2, 2).
// Pre-activation sigma <= ~0.3 => clamp region is >6-sigma; interior max error ~0.01.
__device__ __forceinline__ float poly_tanh(float x) {
    const float C0 = 0.993654f;
    const float C1 = -0.29463f;
    const float C2 = 0.0695331f;
    const float C3 = -0.00696328f;
    float t = fminf(fmaxf(x, -2.0f), 2.0f);
    float u = t * t;
    float p = fmaf(C3, u, C2);
    p = fmaf(p, u, C1);
    p = fmaf(p, u, C0);
    return t * p;
}

// Pack all per-h weights/biases into one contiguous 36-dword record:
// [0..2] W1m col h, [3] b1m, [4..6] W1g col h, [7] b1g,
// [8..16] W1k col h, [17] b1k, [18..26] W2m row h, [27..29] W2g row h,
// [30..32] W2k row h. One linear uniform stream -> batched s_load from one base.
__global__ void pack_weights(const float* __restrict__ W1m, const float* __restrict__ b1m,
                             const float* __restrict__ W2m,
                             const float* __restrict__ W1g, const float* __restrict__ b1g,
                             const float* __restrict__ W2g,
                             const float* __restrict__ W1k, const float* __restrict__ b1k,
                             const float* __restrict__ W2k,
                             float* __restrict__ rec)
{
    const int h = blockIdx.x * blockDim.x + threadIdx.x;
    if (h >= HDIM) return;
    float* r = rec + h * REC;
    r[0] = W1m[0*HDIM+h]; r[1] = W1m[1*HDIM+h]; r[2] = W1m[2*HDIM+h]; r[3] = b1m[h];
    r[4] = W1g[0*HDIM+h]; r[5] = W1g[1*HDIM+h]; r[6] = W1g[2*HDIM+h]; r[7] = b1g[h];
    #pragma unroll
    for (int j = 0; j < 9; ++j) r[8+j] = W1k[j*HDIM+h];
    r[17] = b1k[h];
    #pragma unroll
    for (int j = 0; j < 9; ++j) r[18+j] = W2m[h*9+j];
    r[27] = W2g[h*3+0]; r[28] = W2g[h*3+1]; r[29] = W2g[h*3+2];
    r[30] = W2k[h*3+0]; r[31] = W2k[h*3+1]; r[32] = W2k[h*3+2];
    r[33] = 0.f; r[34] = 0.f; r[35] = 0.f;
}

__global__ __launch_bounds__(256, 4) void dyn_kernel(
    const float* __restrict__ rec,
    const float* __restrict__ q, const float* __restrict__ q_dot,
    const float* __restrict__ s, const float* __restrict__ s_Ddot,
    const float* __restrict__ tau,
    const float* __restrict__ fv, const float* __restrict__ fc,
    const float* __restrict__ b2m, const float* __restrict__ b2g,
    const float* __restrict__ b2k,
    float* __restrict__ out, int n)
{
    // Waves 1..3 deposit partials; wave 0 keeps its own in registers.
    __shared__ float part[WAVES_PER_BLOCK - 1][SPB][PSTRIDE];

    const int lane = threadIdx.x & 63;
    // Wave id in SGPR so the packed-record address stream is provably
    // wave-uniform -> s_load (SMEM broadcast), not per-lane VMEM.
    const int w = __builtin_amdgcn_readfirstlane((int)(threadIdx.x >> 6));
    const int base = blockIdx.x * SPB;

    float in[SPL][9];
    float acc[SPL][NPART];
    #pragma unroll
    for (int ss = 0; ss < SPL; ++ss) {
        const int i = base + ss*64 + lane;
        const int ic = (i < n) ? i : 0;
        in[ss][0] = q[3*ic+0];      in[ss][1] = q[3*ic+1];      in[ss][2] = q[3*ic+2];
        in[ss][3] = s[3*ic+0];      in[ss][4] = s[3*ic+1];      in[ss][5] = s[3*ic+2];
        in[ss][6] = s_Ddot[3*ic+0]; in[ss][7] = s_Ddot[3*ic+1]; in[ss][8] = s_Ddot[3*ic+2];
        #pragma unroll
        for (int c = 0; c < NPART; ++c) acc[ss][c] = 0.f;
    }

    const float* rp = rec + (size_t)(w * HCHUNK) * REC;

    #pragma unroll 2
    for (int hh = 0; hh < HCHUNK; ++hh) {
        // One linear 33-dword uniform load (wv[] -> SGPRs).
        float wv[33];
        #pragma unroll
        for (int j = 0; j < 33; ++j) wv[j] = rp[j];
        rp += REC;

        #pragma unroll
        for (int ss = 0; ss < SPL; ++ss) {
            float pm = fmaf(in[ss][2], wv[2], fmaf(in[ss][1], wv[1], fmaf(in[ss][0], wv[0], wv[3])));
            float pg = fmaf(in[ss][2], wv[6], fmaf(in[ss][1], wv[5], fmaf(in[ss][0], wv[4], wv[7])));
            float pk = wv[17];
            #pragma unroll
            for (int j = 0; j < 9; ++j) pk = fmaf(in[ss][j], wv[8+j], pk);

            const float hm = poly_tanh(pm);
            const float hg = poly_tanh(pg);
            const float hk = poly_tanh(pk);

            #pragma unroll
            for (int j = 0; j < 9; ++j) acc[ss][j]    = fmaf(hm, wv[18+j], acc[ss][j]);
            #pragma unroll
            for (int j = 0; j < 3; ++j) acc[ss][9+j]  = fmaf(hg, wv[27+j], acc[ss][9+j]);
            #pragma unroll
            for (int j = 0; j < 3; ++j) acc[ss][12+j] = fmaf(hk, wv[30+j], acc[ss][12+j]);
        }
    }

    if (w != 0) {
        #pragma unroll
        for (int ss = 0; ss < SPL; ++ss) {
            float* dst = &part[w-1][ss*64 + lane][0];
            #pragma unroll
            for (int c = 0; c < NPART; ++c) dst[c] = acc[ss][c];
        }
    }
    __syncthreads();
    if (w != 0) return;

    // Wave 0: fold in the three deposited partial sets.
    #pragma unroll
    for (int ss = 0; ss < SPL; ++ss) {
        const int slot = ss*64 + lane;
        #pragma unroll
        for (int c = 0; c < NPART; ++c)
            acc[ss][c] += part[0][slot][c] + part[1][slot][c] + part[2][slot][c];
    }

    // Epilogue scalars (wave-uniform).
    const float fv0 = fv[0], fv1 = fv[1], fv2 = fv[2];
    const float fc0 = fc[0], fc1 = fc[1], fc2 = fc[2];
    const float e2m0 = b2m[0], e2m1 = b2m[1], e2m2 = b2m[2],
                e2m3 = b2m[3], e2m4 = b2m[4], e2m5 = b2m[5],
                e2m6 = b2m[6], e2m7 = b2m[7], e2m8 = b2m[8];
    const float e2g0 = b2g[0], e2g1 = b2g[1], e2g2 = b2g[2];
    const float e2k0 = b2k[0], e2k1 = b2k[1], e2k2 = b2k[2];

    #pragma unroll
    for (int ss = 0; ss < SPL; ++ss) {
        const int i = base + ss*64 + lane;
        if (i >= n) continue;

        const float bM0 = acc[ss][0] + e2m0, bM1 = acc[ss][1] + e2m1, bM2 = acc[ss][2] + e2m2;
        const float bM3 = acc[ss][3] + e2m3, bM4 = acc[ss][4] + e2m4, bM5 = acc[ss][5] + e2m5;
        const float bM6 = acc[ss][6] + e2m6, bM7 = acc[ss][7] + e2m7, bM8 = acc[ss][8] + e2m8;
        const float bG0 = acc[ss][9]  + e2g0, bG1 = acc[ss][10] + e2g1, bG2 = acc[ss][11] + e2g2;
        const float bK0 = acc[ss][12] + e2k0, bK1 = acc[ss][13] + e2k1, bK2 = acc[ss][14] + e2k2;

        // M = Mraw @ Mraw^T + eps*I
        const float m00 = bM0*bM0 + bM1*bM1 + bM2*bM2 + EPS_DIAG;
        const float m01 = bM0*bM3 + bM1*bM4 + bM2*bM5;
        const float m02 = bM0*bM6 + bM1*bM7 + bM2*bM8;
        const float m11 = bM3*bM3 + bM4*bM4 + bM5*bM5 + EPS_DIAG;
        const float m12 = bM3*bM6 + bM4*bM7 + bM5*bM8;
        const float m22 = bM6*bM6 + bM7*bM7 + bM8*bM8 + EPS_DIAG;

        // rhs = -G + KAB - fv*q_dot - fc*sign(q_dot) + tau
        const float qd0 = q_dot[3*i+0], qd1 = q_dot[3*i+1], qd2 = q_dot[3*i+2];
        const float t0 = tau[3*i+0], t1 = tau[3*i+1], t2 = tau[3*i+2];
        const float sg0 = (qd0 > 0.f) ? 1.f : ((qd0 < 0.f) ? -1.f : 0.f);
        const float sg1 = (qd1 > 0.f) ? 1.f : ((qd1 < 0.f) ? -1.f : 0.f);
        const float sg2 = (qd2 > 0.f) ? 1.f : ((qd2 < 0.f) ? -1.f : 0.f);
        const float r0 = -bG0 + bK0 - fv0*qd0 - fc0*sg0 + t0;
        const float r1 = -bG1 + bK1 - fv1*qd1 - fc1*sg1 + t1;
        const float r2 = -bG2 + bK2 - fv2*qd2 - fc2*sg2 + t2;

        // Symmetric 3x3 inverse via adjugate (M SPD, det >= ~1e-3).
        const float c00 = m11*m22 - m12*m12;
        const float c01 = m02*m12 - m01*m22;
        const float c02 = m01*m12 - m02*m11;
        const float det = m00*c00 + m01*c01 + m02*c02;
        const float idet = 1.0f / det;
        const float i11 = m00*m22 - m02*m02;
        const float i12 = m01*m02 - m00*m12;
        const float i22 = m00*m11 - m01*m01;

        out[3*i+0] = (c00*r0 + c01*r1 + c02*r2) * idet;
        out[3*i+1] = (c01*r0 + i11*r1 + i12*r2) * idet;
        out[3*i+2] = (c02*r0 + i12*r1 + i22*r2) * idet;
    }
}

extern "C" void kernel_launch(void* const* d_in, const int* in_sizes, int n_in,
                              void* d_out, int out_size, void* d_ws, size_t ws_size,
                              hipStream_t stream) {
    const float* q      = (const float*)d_in[0];
    const float* q_dot  = (const float*)d_in[1];
    const float* s      = (const float*)d_in[2];
    const float* s_Ddot = (const float*)d_in[3];
    const float* tau    = (const float*)d_in[4];
    const float* fv     = (const float*)d_in[5];
    const float* fc     = (const float*)d_in[6];
    const float* W1m    = (const float*)d_in[7];
    const float* b1m    = (const float*)d_in[8];
    const float* W2m    = (const float*)d_in[9];
    const float* b2m    = (const float*)d_in[10];
    const float* W1g    = (const float*)d_in[11];
    const float* b1g    = (const float*)d_in[12];
    const float* W2g    = (const float*)d_in[13];
    const float* b2g    = (const float*)d_in[14];
    const float* W1k    = (const float*)d_in[15];
    const float* b1k    = (const float*)d_in[16];
    const float* W2k    = (const float*)d_in[17];
    const float* b2k    = (const float*)d_in[18];
    float* out = (float*)d_out;
    float* rec = (float*)d_ws;               // needs HDIM*REC*4 = 73728 B

    const int n = in_sizes[0] / 3;           // B = 131072

    pack_weights<<<(HDIM + 255) / 256, 256, 0, stream>>>(
        W1m, b1m, W2m, W1g, b1g, W2g, W1k, b1k, W2k, rec);

    const int blocks = (n + SPB - 1) / SPB;  // 1024 blocks x 256 threads
    dyn_kernel<<<blocks, 256, 0, stream>>>(rec, q, q_dot, s, s_Ddot, tau, fv, fc,
                                           b2m, b2g, b2k, out, n);
}

// Round 9
// 161.155 us; speedup vs baseline: 1.0737x; 1.0104x over previous
//
#include <hip/hip_runtime.h>
#include <hip/hip_fp16.h>
#include <math.h>

#define HDIM 512
#define WAVES_PER_BLOCK 4
#define HCHUNK (HDIM / WAVES_PER_BLOCK)   // 128 h per wave
#define HPAIRS (HCHUNK / 2)               // 64 h-pairs per wave
#define NHPAIR (HDIM / 2)                 // 256 h-pairs total
#define SPL 2                             // samples per lane
#define SPB (64 * SPL)                    // 128 samples per block
#define EPS_DIAG 0.1f
#define NPART 15
#define PSTRIDE 17                        // odd -> <=2-way LDS aliasing (free)
#define RECW 36                           // dwords per h-pair record (33 used + 3 pad)

// NOTE: __builtin_amdgcn_cvt_pkrtz / fdot2 use the __fp16 vector type on this
// toolchain (NOT _Float16) — R8 failed to compile on that mismatch.
typedef __fp16 h2 __attribute__((ext_vector_type(2)));

__device__ __forceinline__ h2 f2h2(float a, float b) {
    return __builtin_amdgcn_cvt_pkrtz(a, b);   // v_cvt_pkrtz_f16_f32
}

#if __has_builtin(__builtin_amdgcn_fdot2)
__device__ __forceinline__ float hdot2(h2 a, h2 b, float c) {
    return __builtin_amdgcn_fdot2(a, b, c, false);   // v_dot2_f32_f16, fp32 accum
}
#else
// Correctness fallback if fdot2 is unavailable on this toolchain.
__device__ __forceinline__ float hdot2(h2 a, h2 b, float c) {
    return fmaf((float)a[0], (float)b[0], fmaf((float)a[1], (float)b[1], c));
}
#endif

// Odd degree-7 poly tanh on clamp(x,-2,2), evaluated on a packed f16 pair.
// 7 pk-ops per PAIR (vs 12 scalar-f32 ops). f16 eval adds <~0.003 abs error
// on top of the ~0.01 poly error — well within the 0.91 threshold budget.
__device__ __forceinline__ h2 tanh2(h2 x) {
    const h2 HI = {(__fp16)2.0f,        (__fp16)2.0f};
    const h2 LO = {(__fp16)-2.0f,       (__fp16)-2.0f};
    const h2 C0 = {(__fp16)0.993654f,   (__fp16)0.993654f};
    const h2 C1 = {(__fp16)-0.29463f,   (__fp16)-0.29463f};
    const h2 C2 = {(__fp16)0.0695331f,  (__fp16)0.0695331f};
    const h2 C3 = {(__fp16)-0.00696328f,(__fp16)-0.00696328f};
    h2 t = __builtin_elementwise_min(__builtin_elementwise_max(x, LO), HI);
    h2 u = t * t;
    h2 p = __builtin_elementwise_fma(C3, u, C2);
    p = __builtin_elementwise_fma(p, u, C1);
    p = __builtin_elementwise_fma(p, u, C0);
    return t * p;
}

// Per h-PAIR packed-f16 record (33 dwords, each = one half2):
//  [0..3]   m layer1: h0:(w0,w1),(w2,b)  h1:(w0,w1),(w2,b)
//  [4..7]   g layer1: same
//  [8..12]  k layer1 h0: (k0,k1),(k2,k3),(k4,k5),(k6,k7),(k8,b)
//  [13..17] k layer1 h1: same
//  [18..26] W2m pairs: (W2m[h0][j], W2m[h1][j])  j=0..8
//  [27..29] W2g pairs, [30..32] W2k pairs
// Biases folded into layer1 via input component 1.0.
__global__ void pack_weights(const float* __restrict__ W1m, const float* __restrict__ b1m,
                             const float* __restrict__ W2m,
                             const float* __restrict__ W1g, const float* __restrict__ b1g,
                             const float* __restrict__ W2g,
                             const float* __restrict__ W1k, const float* __restrict__ b1k,
                             const float* __restrict__ W2k,
                             unsigned int* __restrict__ rec)
{
    const int hp = blockIdx.x * blockDim.x + threadIdx.x;
    if (hp >= NHPAIR) return;
    const int h0 = 2 * hp, h1 = 2 * hp + 1;
    unsigned int* r = rec + hp * RECW;

#define PK(a, b) __builtin_bit_cast(unsigned int, __builtin_amdgcn_cvt_pkrtz((a), (b)))
    r[0] = PK(W1m[0*HDIM+h0], W1m[1*HDIM+h0]);
    r[1] = PK(W1m[2*HDIM+h0], b1m[h0]);
    r[2] = PK(W1m[0*HDIM+h1], W1m[1*HDIM+h1]);
    r[3] = PK(W1m[2*HDIM+h1], b1m[h1]);
    r[4] = PK(W1g[0*HDIM+h0], W1g[1*HDIM+h0]);
    r[5] = PK(W1g[2*HDIM+h0], b1g[h0]);
    r[6] = PK(W1g[0*HDIM+h1], W1g[1*HDIM+h1]);
    r[7] = PK(W1g[2*HDIM+h1], b1g[h1]);
    r[8]  = PK(W1k[0*HDIM+h0], W1k[1*HDIM+h0]);
    r[9]  = PK(W1k[2*HDIM+h0], W1k[3*HDIM+h0]);
    r[10] = PK(W1k[4*HDIM+h0], W1k[5*HDIM+h0]);
    r[11] = PK(W1k[6*HDIM+h0], W1k[7*HDIM+h0]);
    r[12] = PK(W1k[8*HDIM+h0], b1k[h0]);
    r[13] = PK(W1k[0*HDIM+h1], W1k[1*HDIM+h1]);
    r[14] = PK(W1k[2*HDIM+h1], W1k[3*HDIM+h1]);
    r[15] = PK(W1k[4*HDIM+h1], W1k[5*HDIM+h1]);
    r[16] = PK(W1k[6*HDIM+h1], W1k[7*HDIM+h1]);
    r[17] = PK(W1k[8*HDIM+h1], b1k[h1]);
    #pragma unroll
    for (int j = 0; j < 9; ++j) r[18+j] = PK(W2m[h0*9+j], W2m[h1*9+j]);
    #pragma unroll
    for (int j = 0; j < 3; ++j) r[27+j] = PK(W2g[h0*3+j], W2g[h1*3+j]);
    #pragma unroll
    for (int j = 0; j < 3; ++j) r[30+j] = PK(W2k[h0*3+j], W2k[h1*3+j]);
    r[33] = 0u; r[34] = 0u; r[35] = 0u;
#undef PK
}

__global__ __launch_bounds__(256, 4) void dyn_kernel(
    const unsigned int* __restrict__ rec,
    const float* __restrict__ q, const float* __restrict__ q_dot,
    const float* __restrict__ s, const float* __restrict__ s_Ddot,
    const float* __restrict__ tau,
    const float* __restrict__ fv, const float* __restrict__ fc,
    const float* __restrict__ b2m, const float* __restrict__ b2g,
    const float* __restrict__ b2k,
    float* __restrict__ out, int n)
{
    // Waves 1..3 deposit partials; wave 0 keeps its own in registers.
    __shared__ float part[WAVES_PER_BLOCK - 1][SPB][PSTRIDE];

    const int lane = threadIdx.x & 63;
    // Wave id in SGPR so the record address stream is provably wave-uniform
    // -> s_load (SMEM broadcast), not per-lane VMEM.
    const int w = __builtin_amdgcn_readfirstlane((int)(threadIdx.x >> 6));
    const int base = blockIdx.x * SPB;

    // Packed f16 input pairs per sample:
    //  A=(q0,q1) B=(q2,1) for m/g;  C=(q2,s0),D=(s1,s2),E=(d0,d1),F=(d2,1) for k.
    h2 iA[SPL], iB[SPL], iC[SPL], iD[SPL], iE[SPL], iF[SPL];
    float acc[SPL][NPART];
    #pragma unroll
    for (int ss = 0; ss < SPL; ++ss) {
        const int i = base + ss*64 + lane;
        const int ic = (i < n) ? i : 0;
        const float q0 = q[3*ic+0], q1 = q[3*ic+1], q2 = q[3*ic+2];
        const float s0 = s[3*ic+0], s1 = s[3*ic+1], s2 = s[3*ic+2];
        const float d0 = s_Ddot[3*ic+0], d1 = s_Ddot[3*ic+1], d2 = s_Ddot[3*ic+2];
        iA[ss] = f2h2(q0, q1);
        iB[ss] = f2h2(q2, 1.0f);
        iC[ss] = f2h2(q2, s0);
        iD[ss] = f2h2(s1, s2);
        iE[ss] = f2h2(d0, d1);
        iF[ss] = f2h2(d2, 1.0f);
        #pragma unroll
        for (int c = 0; c < NPART; ++c) acc[ss][c] = 0.f;
    }

    const unsigned int* rp = rec + (size_t)(w * HPAIRS) * RECW;

#define WH(j) __builtin_bit_cast(h2, wv[(j)])
    #pragma unroll 2
    for (int hp = 0; hp < HPAIRS; ++hp) {
        unsigned int wv[33];
        #pragma unroll
        for (int j = 0; j < 33; ++j) wv[j] = rp[j];   // uniform -> SGPRs
        rp += RECW;

        #pragma unroll
        for (int ss = 0; ss < SPL; ++ss) {
            // Layer 1 (biases folded): 18 dot2 per h-pair.
            const float pm0 = hdot2(iB[ss], WH(1),  hdot2(iA[ss], WH(0),  0.f));
            const float pm1 = hdot2(iB[ss], WH(3),  hdot2(iA[ss], WH(2),  0.f));
            const float pg0 = hdot2(iB[ss], WH(5),  hdot2(iA[ss], WH(4),  0.f));
            const float pg1 = hdot2(iB[ss], WH(7),  hdot2(iA[ss], WH(6),  0.f));
            const float pk0 = hdot2(iF[ss], WH(12), hdot2(iE[ss], WH(11),
                              hdot2(iD[ss], WH(10), hdot2(iC[ss], WH(9),
                              hdot2(iA[ss], WH(8),  0.f)))));
            const float pk1 = hdot2(iF[ss], WH(17), hdot2(iE[ss], WH(16),
                              hdot2(iD[ss], WH(15), hdot2(iC[ss], WH(14),
                              hdot2(iA[ss], WH(13), 0.f)))));

            // Activations for the h-pair, packed (3 cvt + 21 pk-ops).
            const h2 am = tanh2(f2h2(pm0, pm1));
            const h2 ag = tanh2(f2h2(pg0, pg1));
            const h2 ak = tanh2(f2h2(pk0, pk1));

            // Layer 2: 15 dot2 per h-pair (reduces both h's at once).
            #pragma unroll
            for (int j = 0; j < 9; ++j) acc[ss][j]    = hdot2(am, WH(18+j), acc[ss][j]);
            #pragma unroll
            for (int j = 0; j < 3; ++j) acc[ss][9+j]  = hdot2(ag, WH(27+j), acc[ss][9+j]);
            #pragma unroll
            for (int j = 0; j < 3; ++j) acc[ss][12+j] = hdot2(ak, WH(30+j), acc[ss][12+j]);
        }
    }
#undef WH

    if (w != 0) {
        #pragma unroll
        for (int ss = 0; ss < SPL; ++ss) {
            float* dst = &part[w-1][ss*64 + lane][0];
            #pragma unroll
            for (int c = 0; c < NPART; ++c) dst[c] = acc[ss][c];
        }
    }
    __syncthreads();
    if (w != 0) return;

    // Wave 0: fold in the three deposited partial sets.
    #pragma unroll
    for (int ss = 0; ss < SPL; ++ss) {
        const int slot = ss*64 + lane;
        #pragma unroll
        for (int c = 0; c < NPART; ++c)
            acc[ss][c] += part[0][slot][c] + part[1][slot][c] + part[2][slot][c];
    }

    // Epilogue scalars (wave-uniform).
    const float fv0 = fv[0], fv1 = fv[1], fv2 = fv[2];
    const float fc0 = fc[0], fc1 = fc[1], fc2 = fc[2];
    const float e2m0 = b2m[0], e2m1 = b2m[1], e2m2 = b2m[2],
                e2m3 = b2m[3], e2m4 = b2m[4], e2m5 = b2m[5],
                e2m6 = b2m[6], e2m7 = b2m[7], e2m8 = b2m[8];
    const float e2g0 = b2g[0], e2g1 = b2g[1], e2g2 = b2g[2];
    const float e2k0 = b2k[0], e2k1 = b2k[1], e2k2 = b2k[2];

    #pragma unroll
    for (int ss = 0; ss < SPL; ++ss) {
        const int i = base + ss*64 + lane;
        if (i >= n) continue;

        const float bM0 = acc[ss][0] + e2m0, bM1 = acc[ss][1] + e2m1, bM2 = acc[ss][2] + e2m2;
        const float bM3 = acc[ss][3] + e2m3, bM4 = acc[ss][4] + e2m4, bM5 = acc[ss][5] + e2m5;
        const float bM6 = acc[ss][6] + e2m6, bM7 = acc[ss][7] + e2m7, bM8 = acc[ss][8] + e2m8;
        const float bG0 = acc[ss][9]  + e2g0, bG1 = acc[ss][10] + e2g1, bG2 = acc[ss][11] + e2g2;
        const float bK0 = acc[ss][12] + e2k0, bK1 = acc[ss][13] + e2k1, bK2 = acc[ss][14] + e2k2;

        // M = Mraw @ Mraw^T + eps*I
        const float m00 = bM0*bM0 + bM1*bM1 + bM2*bM2 + EPS_DIAG;
        const float m01 = bM0*bM3 + bM1*bM4 + bM2*bM5;
        const float m02 = bM0*bM6 + bM1*bM7 + bM2*bM8;
        const float m11 = bM3*bM3 + bM4*bM4 + bM5*bM5 + EPS_DIAG;
        const float m12 = bM3*bM6 + bM4*bM7 + bM5*bM8;
        const float m22 = bM6*bM6 + bM7*bM7 + bM8*bM8 + EPS_DIAG;

        // rhs = -G + KAB - fv*q_dot - fc*sign(q_dot) + tau
        const float qd0 = q_dot[3*i+0], qd1 = q_dot[3*i+1], qd2 = q_dot[3*i+2];
        const float t0 = tau[3*i+0], t1 = tau[3*i+1], t2 = tau[3*i+2];
        const float sg0 = (qd0 > 0.f) ? 1.f : ((qd0 < 0.f) ? -1.f : 0.f);
        const float sg1 = (qd1 > 0.f) ? 1.f : ((qd1 < 0.f) ? -1.f : 0.f);
        const float sg2 = (qd2 > 0.f) ? 1.f : ((qd2 < 0.f) ? -1.f : 0.f);
        const float r0 = -bG0 + bK0 - fv0*qd0 - fc0*sg0 + t0;
        const float r1 = -bG1 + bK1 - fv1*qd1 - fc1*sg1 + t1;
        const float r2 = -bG2 + bK2 - fv2*qd2 - fc2*sg2 + t2;

        // Symmetric 3x3 inverse via adjugate (M SPD, det >= ~1e-3).
        const float c00 = m11*m22 - m12*m12;
        const float c01 = m02*m12 - m01*m22;
        const float c02 = m01*m12 - m02*m11;
        const float det = m00*c00 + m01*c01 + m02*c02;
        const float idet = 1.0f / det;
        const float i11 = m00*m22 - m02*m02;
        const float i12 = m01*m02 - m00*m12;
        const float i22 = m00*m11 - m01*m01;

        out[3*i+0] = (c00*r0 + c01*r1 + c02*r2) * idet;
        out[3*i+1] = (c01*r0 + i11*r1 + i12*r2) * idet;
        out[3*i+2] = (c02*r0 + i12*r1 + i22*r2) * idet;
    }
}

extern "C" void kernel_launch(void* const* d_in, const int* in_sizes, int n_in,
                              void* d_out, int out_size, void* d_ws, size_t ws_size,
                              hipStream_t stream) {
    const float* q      = (const float*)d_in[0];
    const float* q_dot  = (const float*)d_in[1];
    const float* s      = (const float*)d_in[2];
    const float* s_Ddot = (const float*)d_in[3];
    const float* tau    = (const float*)d_in[4];
    const float* fv     = (const float*)d_in[5];
    const float* fc     = (const float*)d_in[6];
    const float* W1m    = (const float*)d_in[7];
    const float* b1m    = (const float*)d_in[8];
    const float* W2m    = (const float*)d_in[9];
    const float* b2m    = (const float*)d_in[10];
    const float* W1g    = (const float*)d_in[11];
    const float* b1g    = (const float*)d_in[12];
    const float* W2g    = (const float*)d_in[13];
    const float* b2g    = (const float*)d_in[14];
    const float* W1k    = (const float*)d_in[15];
    const float* b1k    = (const float*)d_in[16];
    const float* W2k    = (const float*)d_in[17];
    const float* b2k    = (const float*)d_in[18];
    float* out = (float*)d_out;
    unsigned int* rec = (unsigned int*)d_ws;   // needs NHPAIR*RECW*4 = 36864 B

    const int n = in_sizes[0] / 3;             // B = 131072

    pack_weights<<<(NHPAIR + 255) / 256, 256, 0, stream>>>(
        W1m, b1m, W2m, W1g, b1g, W2g, W1k, b1k, W2k, rec);

    const int blocks = (n + SPB - 1) / SPB;    // 1024 blocks x 256 threads
    dyn_kernel<<<blocks, 256, 0, stream>>>(rec, q, q_dot, s, s_Ddot, tau, fv, fc,
                                           b2m, b2g, b2k, out, n);
}

// Round 10
// 137.010 us; speedup vs baseline: 1.2629x; 1.1762x over previous
//
#include <hip/hip_runtime.h>
#include <hip/hip_fp16.h>
#include <math.h>

#define HDIM 512
#define NCH1 96              // GEMM1 chunks of 16 hidden (1536/16)
#define NCH2 48              // GEMM2 chunks of 32 hidden (1536/32)
#define EPS_DIAG 0.1f

typedef __fp16 h2 __attribute__((ext_vector_type(2)));
typedef __fp16 h8 __attribute__((ext_vector_type(8)));
typedef float f32x4 __attribute__((ext_vector_type(4)));

__device__ __forceinline__ h2 f2h2(float a, float b) {
    return __builtin_amdgcn_cvt_pkrtz(a, b);   // packs a->low, b->high
}

// Odd degree-7 poly tanh on clamp(x,-2,2), packed f16 pair. Poly err ~0.01.
__device__ __forceinline__ h2 tanh2(h2 x) {
    const h2 HI = {(__fp16)2.0f,        (__fp16)2.0f};
    const h2 LO = {(__fp16)-2.0f,       (__fp16)-2.0f};
    const h2 C0 = {(__fp16)0.993654f,   (__fp16)0.993654f};
    const h2 C1 = {(__fp16)-0.29463f,   (__fp16)-0.29463f};
    const h2 C2 = {(__fp16)0.0695331f,  (__fp16)0.0695331f};
    const h2 C3 = {(__fp16)-0.00696328f,(__fp16)-0.00696328f};
    h2 t = __builtin_elementwise_min(__builtin_elementwise_max(x, LO), HI);
    h2 u = t * t;
    h2 p = __builtin_elementwise_fma(C3, u, C2);
    p = __builtin_elementwise_fma(p, u, C1);
    p = __builtin_elementwise_fma(p, u, C0);
    return t * p;
}

// Pack weights into exact MFMA fragment order (f16).
// Combined hidden: [0,512)=m-net, [512,1024)=g-net, [1024,1536)=k-net.
// X layout (K=32, 10 used): x = [q0,q1,q2,s0,s1,s2,d0,d1,d2,1, 0...].
// frag1[c][lane][j] = W1c[k=(lane>>4)*8+j][h=c*16+(lane&15)]          (c=0..95)
// frag2[t][lane][j] = W2c[hid][n=lane&15], hid = t*32+((kp&1)<<4)+(kp>>1),
//   kp=(lane>>4)*8+j — the (c0,c1) column interleave matching the LDS
//   transpose buffer where dword col h holds (act_h, act_{h+16}).
__global__ void pack_frags(const float* __restrict__ W1m, const float* __restrict__ b1m,
                           const float* __restrict__ W2m,
                           const float* __restrict__ W1g, const float* __restrict__ b1g,
                           const float* __restrict__ W2g,
                           const float* __restrict__ W1k, const float* __restrict__ b1k,
                           const float* __restrict__ W2k,
                           __fp16* __restrict__ frag)
{
    const int tid = blockIdx.x * blockDim.x + threadIdx.x;
    if (tid >= (NCH1 + NCH2) * 64) return;
    const int c = tid >> 6, l = tid & 63;
    __fp16* dst = frag + (size_t)tid * 8;
    if (c < NCH1) {
        const int h = c * 16 + (l & 15);
        #pragma unroll
        for (int j = 0; j < 8; ++j) {
            const int k = (l >> 4) * 8 + j;
            float v = 0.f;
            if (h < 512) {
                if (k < 3) v = W1m[k*HDIM + h];
                else if (k == 9) v = b1m[h];
            } else if (h < 1024) {
                const int hh = h - 512;
                if (k < 3) v = W1g[k*HDIM + hh];
                else if (k == 9) v = b1g[hh];
            } else {
                const int hh = h - 1024;
                if (k < 9) v = W1k[k*HDIM + hh];
                else if (k == 9) v = b1k[hh];
            }
            dst[j] = (__fp16)v;
        }
    } else {
        const int t = c - NCH1;
        const int nOut = l & 15;
        #pragma unroll
        for (int j = 0; j < 8; ++j) {
            const int kp = (l >> 4) * 8 + j;                       // 0..31
            const int hid = t*32 + ((kp & 1) << 4) + (kp >> 1);    // interleaved
            float v = 0.f;
            if (hid < 512)       { if (nOut < 9)                v = W2m[hid*9 + nOut]; }
            else if (hid < 1024) { if (nOut >= 9 && nOut < 12)  v = W2g[(hid-512)*3 + (nOut-9)]; }
            else                 { if (nOut >= 12 && nOut < 15) v = W2k[(hid-1024)*3 + (nOut-12)]; }
            dst[j] = (__fp16)v;
        }
    }
}

__global__ __launch_bounds__(256, 6) void dyn_kernel(
    const __fp16* __restrict__ frag,
    const float* __restrict__ q, const float* __restrict__ q_dot,
    const float* __restrict__ s, const float* __restrict__ s_Ddot,
    const float* __restrict__ tau,
    const float* __restrict__ fv, const float* __restrict__ fc,
    const float* __restrict__ b2m, const float* __restrict__ b2g,
    const float* __restrict__ b2k,
    float* __restrict__ out, int n)
{
    // Per-wave transpose buffer: [sample-row 16][16 dword cols + 4 pad].
    // Dword col h holds packed (act_h, act_{h+16}). Row stride 20 dwords:
    // writes <=2-3 way banks, b128 reads 2-way (free), 16B-aligned reads.
    __shared__ unsigned int tbuf[4][16][20];
    __shared__ float ebuf[4][16][17];

    const int lane = threadIdx.x & 63;
    const int w    = threadIdx.x >> 6;
    const int col  = lane & 15;
    const int quad = lane >> 4;
    const int base16 = (blockIdx.x * 4 + w) * 16;

    // ---- A fragment: A[m=lane&15][k=quad*8+j] (m120-verified layout) ----
    int sm = base16 + col; if (sm >= n) sm = n - 1;
    const float q0 = q[3*sm+0], q1 = q[3*sm+1], q2 = q[3*sm+2];
    const float s0 = s[3*sm+0], s1 = s[3*sm+1], s2 = s[3*sm+2];
    const float d0 = s_Ddot[3*sm+0], d1 = s_Ddot[3*sm+1], d2 = s_Ddot[3*sm+2];
    const bool z0 = (quad == 0), z1 = (quad == 1);
    h8 ax;
    ax[0] = (__fp16)(z0 ? q0 : (z1 ? d2  : 0.f));
    ax[1] = (__fp16)(z0 ? q1 : (z1 ? 1.f : 0.f));
    ax[2] = (__fp16)(z0 ? q2 : 0.f);
    ax[3] = (__fp16)(z0 ? s0 : 0.f);
    ax[4] = (__fp16)(z0 ? s1 : 0.f);
    ax[5] = (__fp16)(z0 ? s2 : 0.f);
    ax[6] = (__fp16)(z0 ? d0 : 0.f);
    ax[7] = (__fp16)(z0 ? d1 : 0.f);

    const f32x4 zero4 = {0.f, 0.f, 0.f, 0.f};
    f32x4 acc = zero4;

    const h8* fw1 = (const h8*)frag + lane;
    const h8* fw2 = (const h8*)frag + (size_t)NCH1 * 64 + lane;

    // 1-deep software pipeline on the (L2-resident) weight fragments.
    h8 w1a = fw1[0], w1b = fw1[64], w2v = fw2[0];
    for (int t = 0; t < NCH2; ++t) {
        h8 nw1a, nw1b, nw2;
        const int tn = t + 1;
        if (tn < NCH2) {
            nw1a = fw1[(2*tn    ) * 64];
            nw1b = fw1[(2*tn + 1) * 64];
            nw2  = fw2[tn * 64];
        }
        // GEMM1: pre-act for 32 hidden (2 chunks of 16). D: row(sample)=quad*4+r, col(h)=lane&15.
        f32x4 p0 = __builtin_amdgcn_mfma_f32_16x16x32_f16(ax, w1a, zero4, 0, 0, 0);
        f32x4 p1 = __builtin_amdgcn_mfma_f32_16x16x32_f16(ax, w1b, zero4, 0, 0, 0);
        // tanh (packed pairs h,h+16) -> LDS transpose (4x ds_write_b32).
        #pragma unroll
        for (int r = 0; r < 4; ++r) {
            const h2 hv = tanh2(f2h2(p0[r], p1[r]));
            tbuf[w][quad*4 + r][col] = __builtin_bit_cast(unsigned int, hv);
        }
        asm volatile("s_waitcnt lgkmcnt(0)" ::: "memory");  // cross-lane LDS dep
        // A2[m=lane&15][k'=quad*8+j]: 8 contiguous halves -> ds_read_b128.
        const h8 a2 = *(const h8*)&tbuf[w][col][quad * 4];
        acc = __builtin_amdgcn_mfma_f32_16x16x32_f16(a2, w2v, acc, 0, 0, 0);
        asm volatile("" ::: "memory");                      // keep next writes after read
        w1a = nw1a; w1b = nw1b; w2v = nw2;
    }

    // ---- Epilogue: gather each sample's 15 outputs via LDS, then 3x3 solve ----
    #pragma unroll
    for (int r = 0; r < 4; ++r)
        ebuf[w][quad*4 + r][col] = acc[r];
    asm volatile("s_waitcnt lgkmcnt(0)" ::: "memory");

    if (lane < 16) {
        const int i = base16 + lane;
        if (i < n) {
            const float* R = ebuf[w][lane];
            const float bM0 = R[0]  + b2m[0], bM1 = R[1]  + b2m[1], bM2 = R[2]  + b2m[2];
            const float bM3 = R[3]  + b2m[3], bM4 = R[4]  + b2m[4], bM5 = R[5]  + b2m[5];
            const float bM6 = R[6]  + b2m[6], bM7 = R[7]  + b2m[7], bM8 = R[8]  + b2m[8];
            const float bG0 = R[9]  + b2g[0], bG1 = R[10] + b2g[1], bG2 = R[11] + b2g[2];
            const float bK0 = R[12] + b2k[0], bK1 = R[13] + b2k[1], bK2 = R[14] + b2k[2];

            // M = Mraw @ Mraw^T + eps*I
            const float m00 = bM0*bM0 + bM1*bM1 + bM2*bM2 + EPS_DIAG;
            const float m01 = bM0*bM3 + bM1*bM4 + bM2*bM5;
            const float m02 = bM0*bM6 + bM1*bM7 + bM2*bM8;
            const float m11 = bM3*bM3 + bM4*bM4 + bM5*bM5 + EPS_DIAG;
            const float m12 = bM3*bM6 + bM4*bM7 + bM5*bM8;
            const float m22 = bM6*bM6 + bM7*bM7 + bM8*bM8 + EPS_DIAG;

            // rhs = -G + KAB - fv*q_dot - fc*sign(q_dot) + tau
            const float qd0 = q_dot[3*i+0], qd1 = q_dot[3*i+1], qd2 = q_dot[3*i+2];
            const float t0 = tau[3*i+0], t1 = tau[3*i+1], t2 = tau[3*i+2];
            const float fv0 = fv[0], fv1 = fv[1], fv2 = fv[2];
            const float fc0 = fc[0], fc1 = fc[1], fc2 = fc[2];
            const float sg0 = (qd0 > 0.f) ? 1.f : ((qd0 < 0.f) ? -1.f : 0.f);
            const float sg1 = (qd1 > 0.f) ? 1.f : ((qd1 < 0.f) ? -1.f : 0.f);
            const float sg2 = (qd2 > 0.f) ? 1.f : ((qd2 < 0.f) ? -1.f : 0.f);
            const float r0 = -bG0 + bK0 - fv0*qd0 - fc0*sg0 + t0;
            const float r1 = -bG1 + bK1 - fv1*qd1 - fc1*sg1 + t1;
            const float r2 = -bG2 + bK2 - fv2*qd2 - fc2*sg2 + t2;

            // Symmetric 3x3 inverse via adjugate (M SPD, det >= ~1e-3).
            const float c00 = m11*m22 - m12*m12;
            const float c01 = m02*m12 - m01*m22;
            const float c02 = m01*m12 - m02*m11;
            const float det = m00*c00 + m01*c01 + m02*c02;
            const float idet = 1.0f / det;
            const float i11 = m00*m22 - m02*m02;
            const float i12 = m01*m02 - m00*m12;
            const float i22 = m00*m11 - m01*m01;

            out[3*i+0] = (c00*r0 + c01*r1 + c02*r2) * idet;
            out[3*i+1] = (c01*r0 + i11*r1 + i12*r2) * idet;
            out[3*i+2] = (c02*r0 + i12*r1 + i22*r2) * idet;
        }
    }
}

extern "C" void kernel_launch(void* const* d_in, const int* in_sizes, int n_in,
                              void* d_out, int out_size, void* d_ws, size_t ws_size,
                              hipStream_t stream) {
    const float* q      = (const float*)d_in[0];
    const float* q_dot  = (const float*)d_in[1];
    const float* s      = (const float*)d_in[2];
    const float* s_Ddot = (const float*)d_in[3];
    const float* tau    = (const float*)d_in[4];
    const float* fv     = (const float*)d_in[5];
    const float* fc     = (const float*)d_in[6];
    const float* W1m    = (const float*)d_in[7];
    const float* b1m    = (const float*)d_in[8];
    const float* W2m    = (const float*)d_in[9];
    const float* b2m    = (const float*)d_in[10];
    const float* W1g    = (const float*)d_in[11];
    const float* b1g    = (const float*)d_in[12];
    const float* W2g    = (const float*)d_in[13];
    const float* b2g    = (const float*)d_in[14];
    const float* W1k    = (const float*)d_in[15];
    const float* b1k    = (const float*)d_in[16];
    const float* W2k    = (const float*)d_in[17];
    const float* b2k    = (const float*)d_in[18];
    float* out = (float*)d_out;
    __fp16* frag = (__fp16*)d_ws;   // needs (96+48)*64*8*2 = 147456 B

    const int n = in_sizes[0] / 3;  // B = 131072

    pack_frags<<<((NCH1 + NCH2) * 64 + 255) / 256, 256, 0, stream>>>(
        W1m, b1m, W2m, W1g, b1g, W2g, W1k, b1k, W2k, frag);

    const int blocks = (n + 63) / 64;   // 4 waves/block, 16 samples/wave
    dyn_kernel<<<blocks, 256, 0, stream>>>(frag, q, q_dot, s, s_Ddot, tau, fv, fc,
                                           b2m, b2g, b2k, out, n);
}

// Round 11
// 133.740 us; speedup vs baseline: 1.2938x; 1.0245x over previous
//
#include <hip/hip_runtime.h>
#include <math.h>

#define HDIM 512
#define NCH1 96              // GEMM1 A-chunks (16 hidden rows each), 2 per t
#define NCH2 48              // t-chunks of 32 hidden
#define EPS_DIAG 0.1f

typedef __fp16 h2 __attribute__((ext_vector_type(2)));
typedef __fp16 h8 __attribute__((ext_vector_type(8)));
typedef float f32x4 __attribute__((ext_vector_type(4)));
typedef unsigned int u32x4 __attribute__((ext_vector_type(4)));

__device__ __forceinline__ h2 f2h2(float a, float b) {
    return __builtin_amdgcn_cvt_pkrtz(a, b);   // a->low, b->high
}

// Odd degree-7 poly tanh on clamp(x,-2,2), packed f16 pair. Poly err ~0.01.
__device__ __forceinline__ h2 tanh2(h2 x) {
    const h2 HI = {(__fp16)2.0f,        (__fp16)2.0f};
    const h2 LO = {(__fp16)-2.0f,       (__fp16)-2.0f};
    const h2 C0 = {(__fp16)0.993654f,   (__fp16)0.993654f};
    const h2 C1 = {(__fp16)-0.29463f,   (__fp16)-0.29463f};
    const h2 C2 = {(__fp16)0.0695331f,  (__fp16)0.0695331f};
    const h2 C3 = {(__fp16)-0.00696328f,(__fp16)-0.00696328f};
    h2 t = __builtin_elementwise_min(__builtin_elementwise_max(x, LO), HI);
    h2 u = t * t;
    h2 p = __builtin_elementwise_fma(C3, u, C2);
    p = __builtin_elementwise_fma(p, u, C1);
    p = __builtin_elementwise_fma(p, u, C0);
    return t * p;
}

// Combined first layer W1c[k][hid]: hid in [0,512)=m-net, [512,1024)=g, [1024,1536)=k.
// x vector: [q0,q1,q2,s0,s1,s2,d0,d1,d2,1, 0..] (bias folded at k=9).
__device__ __forceinline__ float w1c_at(int k, int hid,
    const float* W1m, const float* b1m, const float* W1g, const float* b1g,
    const float* W1k, const float* b1k)
{
    if (hid < 512)  { if (k < 3) return W1m[k*HDIM + hid]; if (k == 9) return b1m[hid]; return 0.f; }
    if (hid < 1024) { const int h = hid - 512;
                      if (k < 3) return W1g[k*HDIM + h];  if (k == 9) return b1g[h];  return 0.f; }
    const int h = hid - 1024;
    if (k < 9) return W1k[k*HDIM + h]; if (k == 9) return b1k[h]; return 0.f;
}

// frag1 chunk c (c=2t+phase): A[m=lane&15][k=quad*8+j] with row permutation
//   hid(c,m) = 32t + 8*(m>>2) + (m&3) + 4*phase
// so GEMM1' D lane (col,quad) reg r holds hid 32t + 8*quad + r (phase 0) and
// +4 (phase 1) -> lane-aligned with GEMM2's B[k=quad*8+j] needs. No transpose!
// frag2 chunk t: A[m=out(lane&15)][k=quad*8+j] = W2c[32t + quad*8+j][out].
__global__ void pack_frags(const float* __restrict__ W1m, const float* __restrict__ b1m,
                           const float* __restrict__ W2m,
                           const float* __restrict__ W1g, const float* __restrict__ b1g,
                           const float* __restrict__ W2g,
                           const float* __restrict__ W1k, const float* __restrict__ b1k,
                           const float* __restrict__ W2k,
                           __fp16* __restrict__ frag)
{
    const int tid = blockIdx.x * blockDim.x + threadIdx.x;
    if (tid >= (NCH1 + NCH2) * 64) return;
    const int c = tid >> 6, l = tid & 63;
    const int m = l & 15, kq = l >> 4;
    __fp16* dst = frag + (size_t)tid * 8;
    if (c < NCH1) {
        const int t = c >> 1, phase = c & 1;
        const int hid = 32*t + 8*(m >> 2) + (m & 3) + 4*phase;
        #pragma unroll
        for (int j = 0; j < 8; ++j) {
            const int k = kq*8 + j;
            dst[j] = (__fp16)((k < 10) ? w1c_at(k, hid, W1m, b1m, W1g, b1g, W1k, b1k) : 0.f);
        }
    } else {
        const int t = c - NCH1;
        #pragma unroll
        for (int j = 0; j < 8; ++j) {
            const int hid = 32*t + kq*8 + j;
            float v = 0.f;
            if (hid < 512)       { if (m < 9)             v = W2m[hid*9 + m]; }
            else if (hid < 1024) { if (m >= 9 && m < 12)  v = W2g[(hid-512)*3 + (m-9)]; }
            else                 { if (m >= 12 && m < 15) v = W2k[(hid-1024)*3 + (m-12)]; }
            dst[j] = (__fp16)v;
        }
    }
}

__global__ __launch_bounds__(256, 8) void dyn_kernel(
    const __fp16* __restrict__ frag,
    const float* __restrict__ q, const float* __restrict__ q_dot,
    const float* __restrict__ s, const float* __restrict__ s_Ddot,
    const float* __restrict__ tau,
    const float* __restrict__ fv, const float* __restrict__ fc,
    const float* __restrict__ b2m, const float* __restrict__ b2g,
    const float* __restrict__ b2k,
    float* __restrict__ out, int n)
{
    __shared__ float ebuf[4][16][20];   // epilogue gather only; stride 20 -> aligned b128

    const int lane = threadIdx.x & 63;
    const int w    = threadIdx.x >> 6;
    const int col  = lane & 15;
    const int quad = lane >> 4;
    const int base16 = (blockIdx.x * 4 + w) * 16;

    // GEMM1' B-operand: B[k=quad*8+j][n=sample=col] — per-lane input vector.
    int sm = base16 + col; if (sm >= n) sm = n - 1;
    const float q0 = q[3*sm+0], q1 = q[3*sm+1], q2 = q[3*sm+2];
    const float s0 = s[3*sm+0], s1 = s[3*sm+1], s2 = s[3*sm+2];
    const float d0 = s_Ddot[3*sm+0], d1 = s_Ddot[3*sm+1], d2 = s_Ddot[3*sm+2];
    const bool z0 = (quad == 0), z1 = (quad == 1);
    h8 ax;
    ax[0] = (__fp16)(z0 ? q0 : (z1 ? d2  : 0.f));
    ax[1] = (__fp16)(z0 ? q1 : (z1 ? 1.f : 0.f));
    ax[2] = (__fp16)(z0 ? q2 : 0.f);
    ax[3] = (__fp16)(z0 ? s0 : 0.f);
    ax[4] = (__fp16)(z0 ? s1 : 0.f);
    ax[5] = (__fp16)(z0 ? s2 : 0.f);
    ax[6] = (__fp16)(z0 ? d0 : 0.f);
    ax[7] = (__fp16)(z0 ? d1 : 0.f);

    const f32x4 zero4 = {0.f, 0.f, 0.f, 0.f};
    f32x4 acc = zero4;

    const h8* p1 = (const h8*)frag + lane;                       // frag1, chunk=64 h8
    const h8* p2 = (const h8*)frag + (size_t)NCH1 * 64 + lane;   // frag2

// One t-step: GEMM1' (2 mfma, hidden-major), tanh in packed f16,
// in-register repack into GEMM2's B-fragment, GEMM2 accumulate. Zero LDS.
#define BODY(W1A, W1B, W2V) do {                                              \
        f32x4 pa = __builtin_amdgcn_mfma_f32_16x16x32_f16((W1A), ax, zero4, 0, 0, 0); \
        f32x4 pb = __builtin_amdgcn_mfma_f32_16x16x32_f16((W1B), ax, zero4, 0, 0, 0); \
        const h2 A01 = tanh2(f2h2(pa[0], pa[1]));                             \
        const h2 A23 = tanh2(f2h2(pa[2], pa[3]));                             \
        const h2 B01 = tanh2(f2h2(pb[0], pb[1]));                             \
        const h2 B23 = tanh2(f2h2(pb[2], pb[3]));                             \
        u32x4 uv;                                                             \
        uv[0] = __builtin_bit_cast(unsigned int, A01);                        \
        uv[1] = __builtin_bit_cast(unsigned int, A23);                        \
        uv[2] = __builtin_bit_cast(unsigned int, B01);                        \
        uv[3] = __builtin_bit_cast(unsigned int, B23);                        \
        const h8 a2 = __builtin_bit_cast(h8, uv);                             \
        acc = __builtin_amdgcn_mfma_f32_16x16x32_f16((W2V), a2, acc, 0, 0, 0); \
    } while (0)

    // Unroll-by-2 with ping-pong prefetch; all offsets are immediates
    // (128 h8 = 2048 B, 192 h8 = 3072 B, 64 h8 = 1024 B — all < 4096).
    h8 a0 = p1[0], b0 = p1[64], c0 = p2[0];
    int t = 0;
    for (; t < NCH2 - 2; t += 2) {
        h8 a1 = p1[128], b1 = p1[192], c1 = p2[64];
        p1 += 256; p2 += 128;
        BODY(a0, b0, c0);
        a0 = p1[0]; b0 = p1[64]; c0 = p2[0];
        BODY(a1, b1, c1);
    }
    {   // final pair (t = 46, 47): no t+2 prefetch -> no OOB reads
        h8 a1 = p1[128], b1 = p1[192], c1 = p2[64];
        BODY(a0, b0, c0);
        BODY(a1, b1, c1);
    }
#undef BODY

    // Epilogue: acc lane (col=sample, quad) holds outs {4q..4q+3} -> one b128
    // deposit per lane, then lanes 0..15 gather their sample's 15 outputs.
    // (Wave-local LDS round trip — pattern validated by R10's epilogue.)
    *(f32x4*)(&ebuf[w][col][4*quad]) = acc;
    asm volatile("s_waitcnt lgkmcnt(0)" ::: "memory");

    if (lane < 16) {
        const int i = base16 + lane;
        if (i < n) {
            const float* R = ebuf[w][lane];
            const float bM0 = R[0]  + b2m[0], bM1 = R[1]  + b2m[1], bM2 = R[2]  + b2m[2];
            const float bM3 = R[3]  + b2m[3], bM4 = R[4]  + b2m[4], bM5 = R[5]  + b2m[5];
            const float bM6 = R[6]  + b2m[6], bM7 = R[7]  + b2m[7], bM8 = R[8]  + b2m[8];
            const float bG0 = R[9]  + b2g[0], bG1 = R[10] + b2g[1], bG2 = R[11] + b2g[2];
            const float bK0 = R[12] + b2k[0], bK1 = R[13] + b2k[1], bK2 = R[14] + b2k[2];

            // M = Mraw @ Mraw^T + eps*I
            const float m00 = bM0*bM0 + bM1*bM1 + bM2*bM2 + EPS_DIAG;
            const float m01 = bM0*bM3 + bM1*bM4 + bM2*bM5;
            const float m02 = bM0*bM6 + bM1*bM7 + bM2*bM8;
            const float m11 = bM3*bM3 + bM4*bM4 + bM5*bM5 + EPS_DIAG;
            const float m12 = bM3*bM6 + bM4*bM7 + bM5*bM8;
            const float m22 = bM6*bM6 + bM7*bM7 + bM8*bM8 + EPS_DIAG;

            // rhs = -G + KAB - fv*q_dot - fc*sign(q_dot) + tau
            const float qd0 = q_dot[3*i+0], qd1 = q_dot[3*i+1], qd2 = q_dot[3*i+2];
            const float t0 = tau[3*i+0], t1 = tau[3*i+1], t2 = tau[3*i+2];
            const float fv0 = fv[0], fv1 = fv[1], fv2 = fv[2];
            const float fc0 = fc[0], fc1 = fc[1], fc2 = fc[2];
            const float sg0 = (qd0 > 0.f) ? 1.f : ((qd0 < 0.f) ? -1.f : 0.f);
            const float sg1 = (qd1 > 0.f) ? 1.f : ((qd1 < 0.f) ? -1.f : 0.f);
            const float sg2 = (qd2 > 0.f) ? 1.f : ((qd2 < 0.f) ? -1.f : 0.f);
            const float r0 = -bG0 + bK0 - fv0*qd0 - fc0*sg0 + t0;
            const float r1 = -bG1 + bK1 - fv1*qd1 - fc1*sg1 + t1;
            const float r2 = -bG2 + bK2 - fv2*qd2 - fc2*sg2 + t2;

            // Symmetric 3x3 inverse via adjugate (M SPD, det >= ~1e-3).
            const float c00 = m11*m22 - m12*m12;
            const float c01 = m02*m12 - m01*m22;
            const float c02 = m01*m12 - m02*m11;
            const float det = m00*c00 + m01*c01 + m02*c02;
            const float idet = 1.0f / det;
            const float i11 = m00*m22 - m02*m02;
            const float i12 = m01*m02 - m00*m12;
            const float i22 = m00*m11 - m01*m01;

            out[3*i+0] = (c00*r0 + c01*r1 + c02*r2) * idet;
            out[3*i+1] = (c01*r0 + i11*r1 + i12*r2) * idet;
            out[3*i+2] = (c02*r0 + i12*r1 + i22*r2) * idet;
        }
    }
}

extern "C" void kernel_launch(void* const* d_in, const int* in_sizes, int n_in,
                              void* d_out, int out_size, void* d_ws, size_t ws_size,
                              hipStream_t stream) {
    const float* q      = (const float*)d_in[0];
    const float* q_dot  = (const float*)d_in[1];
    const float* s      = (const float*)d_in[2];
    const float* s_Ddot = (const float*)d_in[3];
    const float* tau    = (const float*)d_in[4];
    const float* fv     = (const float*)d_in[5];
    const float* fc     = (const float*)d_in[6];
    const float* W1m    = (const float*)d_in[7];
    const float* b1m    = (const float*)d_in[8];
    const float* W2m    = (const float*)d_in[9];
    const float* b2m    = (const float*)d_in[10];
    const float* W1g    = (const float*)d_in[11];
    const float* b1g    = (const float*)d_in[12];
    const float* W2g    = (const float*)d_in[13];
    const float* b2g    = (const float*)d_in[14];
    const float* W1k    = (const float*)d_in[15];
    const float* b1k    = (const float*)d_in[16];
    const float* W2k    = (const float*)d_in[17];
    const float* b2k    = (const float*)d_in[18];
    float* out = (float*)d_out;
    __fp16* frag = (__fp16*)d_ws;   // (96+48)*64*8*2 = 147456 B

    const int n = in_sizes[0] / 3;  // B = 131072

    pack_frags<<<((NCH1 + NCH2) * 64 + 255) / 256, 256, 0, stream>>>(
        W1m, b1m, W2m, W1g, b1g, W2g, W1k, b1k, W2k, frag);

    const int blocks = (n + 63) / 64;   // 4 waves/block, 16 samples/wave
    dyn_kernel<<<blocks, 256, 0, stream>>>(frag, q, q_dot, s, s_Ddot, tau, fv, fc,
                                           b2m, b2g, b2k, out, n);
}

// Round 12
// 129.269 us; speedup vs baseline: 1.3385x; 1.0346x over previous
//
#include <hip/hip_runtime.h>
#include <math.h>

#define HDIM 512
#define NCH1 96              // GEMM1 A-chunks (16 hidden rows each), 2 per t
#define NCH2 48              // t-chunks of 32 hidden
#define EPS_DIAG 0.1f

typedef __fp16 h2 __attribute__((ext_vector_type(2)));
typedef __fp16 h8 __attribute__((ext_vector_type(8)));
typedef float f32x4 __attribute__((ext_vector_type(4)));
typedef unsigned int u32x4 __attribute__((ext_vector_type(4)));

__device__ __forceinline__ h2 f2h2(float a, float b) {
    return __builtin_amdgcn_cvt_pkrtz(a, b);   // a->low, b->high
}

// Odd degree-7 poly tanh on clamp(x,-2,2), packed f16 pair. Poly err ~0.01.
__device__ __forceinline__ h2 tanh2(h2 x) {
    const h2 HI = {(__fp16)2.0f,        (__fp16)2.0f};
    const h2 LO = {(__fp16)-2.0f,       (__fp16)-2.0f};
    const h2 C0 = {(__fp16)0.993654f,   (__fp16)0.993654f};
    const h2 C1 = {(__fp16)-0.29463f,   (__fp16)-0.29463f};
    const h2 C2 = {(__fp16)0.0695331f,  (__fp16)0.0695331f};
    const h2 C3 = {(__fp16)-0.00696328f,(__fp16)-0.00696328f};
    h2 t = __builtin_elementwise_min(__builtin_elementwise_max(x, LO), HI);
    h2 u = t * t;
    h2 p = __builtin_elementwise_fma(C3, u, C2);
    p = __builtin_elementwise_fma(p, u, C1);
    p = __builtin_elementwise_fma(p, u, C0);
    return t * p;
}

// Combined first layer W1c[k][hid]: hid in [0,512)=m-net, [512,1024)=g, [1024,1536)=k.
// x vector: [q0,q1,q2,s0,s1,s2,d0,d1,d2,1, 0..] (bias folded at k=9).
__device__ __forceinline__ float w1c_at(int k, int hid,
    const float* W1m, const float* b1m, const float* W1g, const float* b1g,
    const float* W1k, const float* b1k)
{
    if (hid < 512)  { if (k < 3) return W1m[k*HDIM + hid]; if (k == 9) return b1m[hid]; return 0.f; }
    if (hid < 1024) { const int h = hid - 512;
                      if (k < 3) return W1g[k*HDIM + h];  if (k == 9) return b1g[h];  return 0.f; }
    const int h = hid - 1024;
    if (k < 9) return W1k[k*HDIM + h]; if (k == 9) return b1k[h]; return 0.f;
}

// IDENTICAL layout to R11 (verified: absmax 0.25).
// frag1 chunk c (c=2t+phase): A[m=lane&15][k=quad*8+j], hid(c,m)=32t+8*(m>>2)+(m&3)+4*phase.
// frag2 chunk t: A[m=out(lane&15)][k'=quad*8+j] = W2c[32t + quad*8+j][out].
__global__ void pack_frags(const float* __restrict__ W1m, const float* __restrict__ b1m,
                           const float* __restrict__ W2m,
                           const float* __restrict__ W1g, const float* __restrict__ b1g,
                           const float* __restrict__ W2g,
                           const float* __restrict__ W1k, const float* __restrict__ b1k,
                           const float* __restrict__ W2k,
                           __fp16* __restrict__ frag)
{
    const int tid = blockIdx.x * blockDim.x + threadIdx.x;
    if (tid >= (NCH1 + NCH2) * 64) return;
    const int c = tid >> 6, l = tid & 63;
    const int m = l & 15, kq = l >> 4;
    __fp16* dst = frag + (size_t)tid * 8;
    if (c < NCH1) {
        const int t = c >> 1, phase = c & 1;
        const int hid = 32*t + 8*(m >> 2) + (m & 3) + 4*phase;
        #pragma unroll
        for (int j = 0; j < 8; ++j) {
            const int k = kq*8 + j;
            dst[j] = (__fp16)((k < 10) ? w1c_at(k, hid, W1m, b1m, W1g, b1g, W1k, b1k) : 0.f);
        }
    } else {
        const int t = c - NCH1;
        #pragma unroll
        for (int j = 0; j < 8; ++j) {
            const int hid = 32*t + kq*8 + j;
            float v = 0.f;
            if (hid < 512)       { if (m < 9)             v = W2m[hid*9 + m]; }
            else if (hid < 1024) { if (m >= 9 && m < 12)  v = W2g[(hid-512)*3 + (m-9)]; }
            else                 { if (m >= 12 && m < 15) v = W2k[(hid-1024)*3 + (m-12)]; }
            dst[j] = (__fp16)v;
        }
    }
}

__global__ __launch_bounds__(256, 4) void dyn_kernel(
    const __fp16* __restrict__ frag,
    const float* __restrict__ q, const float* __restrict__ q_dot,
    const float* __restrict__ s, const float* __restrict__ s_Ddot,
    const float* __restrict__ tau,
    const float* __restrict__ fv, const float* __restrict__ fc,
    const float* __restrict__ b2m, const float* __restrict__ b2g,
    const float* __restrict__ b2k,
    float* __restrict__ out, int n)
{
    __shared__ float ebuf[4][32][20];   // epilogue gather; stride 20 -> aligned b128, no conflicts (R11)

    const int lane = threadIdx.x & 63;
    const int w    = threadIdx.x >> 6;
    const int col  = lane & 15;
    const int quad = lane >> 4;
    const int base32 = (blockIdx.x * 4 + w) * 32;   // 32 samples per wave (2 tiles)

    // B-operands for GEMM1': B[k=quad*8+j][n=sample=col], one per tile.
    h8 ax0, ax1;
    {
        int sm = base32 + col; if (sm >= n) sm = n - 1;
        const float q0 = q[3*sm+0], q1 = q[3*sm+1], q2 = q[3*sm+2];
        const float s0 = s[3*sm+0], s1 = s[3*sm+1], s2 = s[3*sm+2];
        const float d0 = s_Ddot[3*sm+0], d1 = s_Ddot[3*sm+1], d2 = s_Ddot[3*sm+2];
        const bool z0 = (quad == 0), z1 = (quad == 1);
        ax0[0] = (__fp16)(z0 ? q0 : (z1 ? d2  : 0.f));
        ax0[1] = (__fp16)(z0 ? q1 : (z1 ? 1.f : 0.f));
        ax0[2] = (__fp16)(z0 ? q2 : 0.f);
        ax0[3] = (__fp16)(z0 ? s0 : 0.f);
        ax0[4] = (__fp16)(z0 ? s1 : 0.f);
        ax0[5] = (__fp16)(z0 ? s2 : 0.f);
        ax0[6] = (__fp16)(z0 ? d0 : 0.f);
        ax0[7] = (__fp16)(z0 ? d1 : 0.f);
    }
    {
        int sm = base32 + 16 + col; if (sm >= n) sm = n - 1;
        const float q0 = q[3*sm+0], q1 = q[3*sm+1], q2 = q[3*sm+2];
        const float s0 = s[3*sm+0], s1 = s[3*sm+1], s2 = s[3*sm+2];
        const float d0 = s_Ddot[3*sm+0], d1 = s_Ddot[3*sm+1], d2 = s_Ddot[3*sm+2];
        const bool z0 = (quad == 0), z1 = (quad == 1);
        ax1[0] = (__fp16)(z0 ? q0 : (z1 ? d2  : 0.f));
        ax1[1] = (__fp16)(z0 ? q1 : (z1 ? 1.f : 0.f));
        ax1[2] = (__fp16)(z0 ? q2 : 0.f);
        ax1[3] = (__fp16)(z0 ? s0 : 0.f);
        ax1[4] = (__fp16)(z0 ? s1 : 0.f);
        ax1[5] = (__fp16)(z0 ? s2 : 0.f);
        ax1[6] = (__fp16)(z0 ? d0 : 0.f);
        ax1[7] = (__fp16)(z0 ? d1 : 0.f);
    }

    const f32x4 zero4 = {0.f, 0.f, 0.f, 0.f};
    f32x4 acc0 = zero4, acc1 = zero4;

    const h8* p1 = (const h8*)frag + lane;                       // frag1, chunk=64 h8
    const h8* p2 = (const h8*)frag + (size_t)NCH1 * 64 + lane;   // frag2

// One t-step: 2 GEMM1' MFMAs + 1 GEMM2 MFMA per tile, 2 tiles sharing the
// same weight fragments (halves L2 weight traffic vs R11). Zero LDS in loop.
#define BODY(W1A, W1B, W2V) do {                                              \
        f32x4 pa0 = __builtin_amdgcn_mfma_f32_16x16x32_f16((W1A), ax0, zero4, 0, 0, 0); \
        f32x4 pb0 = __builtin_amdgcn_mfma_f32_16x16x32_f16((W1B), ax0, zero4, 0, 0, 0); \
        f32x4 pa1 = __builtin_amdgcn_mfma_f32_16x16x32_f16((W1A), ax1, zero4, 0, 0, 0); \
        f32x4 pb1 = __builtin_amdgcn_mfma_f32_16x16x32_f16((W1B), ax1, zero4, 0, 0, 0); \
        u32x4 uv;                                                             \
        uv[0] = __builtin_bit_cast(unsigned int, tanh2(f2h2(pa0[0], pa0[1]))); \
        uv[1] = __builtin_bit_cast(unsigned int, tanh2(f2h2(pa0[2], pa0[3]))); \
        uv[2] = __builtin_bit_cast(unsigned int, tanh2(f2h2(pb0[0], pb0[1]))); \
        uv[3] = __builtin_bit_cast(unsigned int, tanh2(f2h2(pb0[2], pb0[3]))); \
        acc0 = __builtin_amdgcn_mfma_f32_16x16x32_f16((W2V), __builtin_bit_cast(h8, uv), acc0, 0, 0, 0); \
        uv[0] = __builtin_bit_cast(unsigned int, tanh2(f2h2(pa1[0], pa1[1]))); \
        uv[1] = __builtin_bit_cast(unsigned int, tanh2(f2h2(pa1[2], pa1[3]))); \
        uv[2] = __builtin_bit_cast(unsigned int, tanh2(f2h2(pb1[0], pb1[1]))); \
        uv[3] = __builtin_bit_cast(unsigned int, tanh2(f2h2(pb1[2], pb1[3]))); \
        acc1 = __builtin_amdgcn_mfma_f32_16x16x32_f16((W2V), __builtin_bit_cast(h8, uv), acc1, 0, 0, 0); \
    } while (0)

    // Unroll-by-2 ping-pong prefetch; all offsets immediates (< 4096 B).
    h8 a0 = p1[0], b0 = p1[64], c0 = p2[0];
    int t = 0;
    for (; t < NCH2 - 2; t += 2) {
        h8 a1 = p1[128], b1 = p1[192], c1 = p2[64];
        p1 += 256; p2 += 128;
        BODY(a0, b0, c0);
        a0 = p1[0]; b0 = p1[64]; c0 = p2[0];
        BODY(a1, b1, c1);
    }
    {   // final pair (t = 46, 47): no t+2 prefetch -> no OOB reads
        h8 a1 = p1[128], b1 = p1[192], c1 = p2[64];
        BODY(a0, b0, c0);
        BODY(a1, b1, c1);
    }
#undef BODY

    // Epilogue: acc lane (col=sample, quad) holds outs {4q..4q+3}. One b128
    // deposit per tile per lane; lanes 0..31 gather their sample's 15 outputs.
    *(f32x4*)(&ebuf[w][col][4*quad])      = acc0;
    *(f32x4*)(&ebuf[w][16 + col][4*quad]) = acc1;
    asm volatile("s_waitcnt lgkmcnt(0)" ::: "memory");

    if (lane < 32) {
        const int i = base32 + lane;
        if (i < n) {
            const float* R = ebuf[w][lane];
            const float bM0 = R[0]  + b2m[0], bM1 = R[1]  + b2m[1], bM2 = R[2]  + b2m[2];
            const float bM3 = R[3]  + b2m[3], bM4 = R[4]  + b2m[4], bM5 = R[5]  + b2m[5];
            const float bM6 = R[6]  + b2m[6], bM7 = R[7]  + b2m[7], bM8 = R[8]  + b2m[8];
            const float bG0 = R[9]  + b2g[0], bG1 = R[10] + b2g[1], bG2 = R[11] + b2g[2];
            const float bK0 = R[12] + b2k[0], bK1 = R[13] + b2k[1], bK2 = R[14] + b2k[2];

            // M = Mraw @ Mraw^T + eps*I
            const float m00 = bM0*bM0 + bM1*bM1 + bM2*bM2 + EPS_DIAG;
            const float m01 = bM0*bM3 + bM1*bM4 + bM2*bM5;
            const float m02 = bM0*bM6 + bM1*bM7 + bM2*bM8;
            const float m11 = bM3*bM3 + bM4*bM4 + bM5*bM5 + EPS_DIAG;
            const float m12 = bM3*bM6 + bM4*bM7 + bM5*bM8;
            const float m22 = bM6*bM6 + bM7*bM7 + bM8*bM8 + EPS_DIAG;

            // rhs = -G + KAB - fv*q_dot - fc*sign(q_dot) + tau
            const float qd0 = q_dot[3*i+0], qd1 = q_dot[3*i+1], qd2 = q_dot[3*i+2];
            const float t0 = tau[3*i+0], t1 = tau[3*i+1], t2 = tau[3*i+2];
            const float fv0 = fv[0], fv1 = fv[1], fv2 = fv[2];
            const float fc0 = fc[0], fc1 = fc[1], fc2 = fc[2];
            const float sg0 = (qd0 > 0.f) ? 1.f : ((qd0 < 0.f) ? -1.f : 0.f);
            const float sg1 = (qd1 > 0.f) ? 1.f : ((qd1 < 0.f) ? -1.f : 0.f);
            const float sg2 = (qd2 > 0.f) ? 1.f : ((qd2 < 0.f) ? -1.f : 0.f);
            const float r0 = -bG0 + bK0 - fv0*qd0 - fc0*sg0 + t0;
            const float r1 = -bG1 + bK1 - fv1*qd1 - fc1*sg1 + t1;
            const float r2 = -bG2 + bK2 - fv2*qd2 - fc2*sg2 + t2;

            // Symmetric 3x3 inverse via adjugate (M SPD, det >= ~1e-3).
            const float c00 = m11*m22 - m12*m12;
            const float c01 = m02*m12 - m01*m22;
            const float c02 = m01*m12 - m02*m11;
            const float det = m00*c00 + m01*c01 + m02*c02;
            const float idet = 1.0f / det;
            const float i11 = m00*m22 - m02*m02;
            const float i12 = m01*m02 - m00*m12;
            const float i22 = m00*m11 - m01*m01;

            out[3*i+0] = (c00*r0 + c01*r1 + c02*r2) * idet;
            out[3*i+1] = (c01*r0 + i11*r1 + i12*r2) * idet;
            out[3*i+2] = (c02*r0 + i12*r1 + i22*r2) * idet;
        }
    }
}

extern "C" void kernel_launch(void* const* d_in, const int* in_sizes, int n_in,
                              void* d_out, int out_size, void* d_ws, size_t ws_size,
                              hipStream_t stream) {
    const float* q      = (const float*)d_in[0];
    const float* q_dot  = (const float*)d_in[1];
    const float* s      = (const float*)d_in[2];
    const float* s_Ddot = (const float*)d_in[3];
    const float* tau    = (const float*)d_in[4];
    const float* fv     = (const float*)d_in[5];
    const float* fc     = (const float*)d_in[6];
    const float* W1m    = (const float*)d_in[7];
    const float* b1m    = (const float*)d_in[8];
    const float* W2m    = (const float*)d_in[9];
    const float* b2m    = (const float*)d_in[10];
    const float* W1g    = (const float*)d_in[11];
    const float* b1g    = (const float*)d_in[12];
    const float* W2g    = (const float*)d_in[13];
    const float* b2g    = (const float*)d_in[14];
    const float* W1k    = (const float*)d_in[15];
    const float* b1k    = (const float*)d_in[16];
    const float* W2k    = (const float*)d_in[17];
    const float* b2k    = (const float*)d_in[18];
    float* out = (float*)d_out;
    __fp16* frag = (__fp16*)d_ws;   // (96+48)*64*8*2 = 147456 B

    const int n = in_sizes[0] / 3;  // B = 131072

    pack_frags<<<((NCH1 + NCH2) * 64 + 255) / 256, 256, 0, stream>>>(
        W1m, b1m, W2m, W1g, b1g, W2g, W1k, b1k, W2k, frag);

    const int blocks = (n + 127) / 128;   // 4 waves/block, 32 samples/wave
    dyn_kernel<<<blocks, 256, 0, stream>>>(frag, q, q_dot, s, s_Ddot, tau, fv, fc,
                                           b2m, b2g, b2k, out, n);
}